// Round 5
// baseline (130.091 us; speedup 1.0000x reference)
//
#include <hip/hip_runtime.h>
#include <hip/hip_bf16.h>

typedef __bf16 bf16;
typedef __bf16 bf16x8 __attribute__((ext_vector_type(8)));
typedef __bf16 bf16x4 __attribute__((ext_vector_type(4)));
typedef float floatx4 __attribute__((ext_vector_type(4)));

// may_alias: LDS P-buffer is written as int (fp8 pack) and read as long
// (MFMA fragment) with NO barrier between (wave-private). Without may_alias,
// TBAA lets the compiler reorder the ds_read above the ds_write (round-3 NaN).
typedef int    aint    __attribute__((may_alias));
typedef long   along   __attribute__((may_alias));
typedef float4 afloat4 __attribute__((may_alias));

#define NPIX 4096
#define BATCH 4
#define LOG2E 1.4426950408889634f

__device__ inline bf16x8 zero8() {
    bf16x8 v;
    #pragma unroll
    for (int i = 0; i < 8; ++i) v[i] = (bf16)0.0f;
    return v;
}

// ---------------------------------------------------------------------------
// Kernel 1: projections via MFMA.  X[16384x64] @ W[64x80] ->
//   fq [16384][8] bf16, gq [16384][8] bf16 (PRE-SCALED by log2e),
//   hT [4][64][4096] fp8 e4m3.
// ---------------------------------------------------------------------------
__global__ __launch_bounds__(256) void proj_kernel(
    const float* __restrict__ x,
    const float* __restrict__ w_f, const float* __restrict__ b_f,
    const float* __restrict__ w_g, const float* __restrict__ b_g,
    const float* __restrict__ w_h, const float* __restrict__ b_h,
    bf16* __restrict__ fq, bf16* __restrict__ gq, unsigned char* __restrict__ hT)
{
    __shared__ bf16 xs[64 * 72];
    __shared__ bf16 wt[80 * 72];
    __shared__ float bs[80];
    const int tid = threadIdx.x;
    const int p0 = blockIdx.x * 64;

    {   // stage x tile 64x64 f32 -> bf16
        const float4* xg = (const float4*)(x + (long)p0 * 64);
        #pragma unroll
        for (int it = 0; it < 4; ++it) {
            int i4 = tid + it * 256;
            float4 v = xg[i4];
            int row = i4 >> 4, c4 = (i4 & 15) * 4;
            bf16x4 pk;
            pk[0] = (bf16)v.x; pk[1] = (bf16)v.y; pk[2] = (bf16)v.z; pk[3] = (bf16)v.w;
            *(bf16x4*)(&xs[row * 72 + c4]) = pk;
        }
    }
    for (int idx = tid; idx < 80 * 64; idx += 256) {
        int n = idx >> 6, c = idx & 63;
        float v = (n < 8) ? w_f[c * 8 + n]
                : (n < 16) ? w_g[c * 8 + (n - 8)]
                : w_h[c * 64 + (n - 16)];
        wt[n * 72 + c] = (bf16)v;
    }
    if (tid < 80)
        bs[tid] = (tid < 8) ? b_f[tid] : (tid < 16) ? b_g[tid - 8] : b_h[tid - 16];
    __syncthreads();

    const int wv = tid >> 6, lane = tid & 63;
    const int quad = lane >> 4, l15 = lane & 15;
    const int b = blockIdx.x >> 6;
    const int n0pix = (p0 & (NPIX - 1)) + wv * 16 + quad * 4;

    bf16x8 a0 = *(const bf16x8*)(&xs[(wv * 16 + l15) * 72 + quad * 8]);
    bf16x8 a1 = *(const bf16x8*)(&xs[(wv * 16 + l15) * 72 + 32 + quad * 8]);

    #pragma unroll
    for (int nt = 0; nt < 5; ++nt) {
        float bias = bs[nt * 16 + l15];
        floatx4 acc = {bias, bias, bias, bias};
        bf16x8 b0 = *(const bf16x8*)(&wt[(nt * 16 + l15) * 72 + quad * 8]);
        bf16x8 b1 = *(const bf16x8*)(&wt[(nt * 16 + l15) * 72 + 32 + quad * 8]);
        acc = __builtin_amdgcn_mfma_f32_16x16x32_bf16(a0, b0, acc, 0, 0, 0);
        acc = __builtin_amdgcn_mfma_f32_16x16x32_bf16(a1, b1, acc, 0, 0, 0);
        if (nt == 0) {
            #pragma unroll
            for (int r = 0; r < 4; ++r) {
                long P = (long)p0 + wv * 16 + quad * 4 + r;
                if (l15 < 8) fq[P * 8 + l15] = (bf16)acc[r];
                else         gq[P * 8 + (l15 - 8)] = (bf16)(acc[r] * LOG2E);
            }
        } else {
            int c = nt * 16 + l15 - 16;
            int pk = __builtin_amdgcn_cvt_pk_fp8_f32(acc[0], acc[1], 0, false);
            pk     = __builtin_amdgcn_cvt_pk_fp8_f32(acc[2], acc[3], pk, true);
            *(aint*)(hT + ((long)b * 64 + c) * NPIX + n0pix) = pk;
        }
    }
}

// ---------------------------------------------------------------------------
// Kernel 2: fp8 MFMA flash attention (no-rescale softmax: |s| small).
// Grid 512 = B(4) x i-tiles(128 of 32 rows). Block 256 thr = 4 waves:
//   grp = wv&1 -> 16 i rows, half = wv>>1 -> j range [half*2048, +2048).
// Per 128-j tile per wave: S^T = F·G^T (bf16 MFMA, g pre-scaled by log2e),
// exp2 -> fp8 pack -> wave-private P; O += P·Ht (fp8 MFMA); den via extra
// MFMA with constant all-ones fp8 B (0x38 = 1.0 e4m3) -> acc[4].
// ---------------------------------------------------------------------------
#define FBASE 0                 // 4 x 2048           = 8192
#define HBASE 8192              // 4 x (64 x 144)     = 36864
#define PBASE 45056             // 4 x (16 x 136)     = 8704
#define LDSTOT 53760
// epilogue reduction buffer aliases the (dead) stage region at smem+0

__global__ __launch_bounds__(256) void attn_kernel(
    const bf16* __restrict__ fq, const bf16* __restrict__ gq,
    const unsigned char* __restrict__ hT, const float* __restrict__ x,
    const float* __restrict__ gamma_p, float* __restrict__ out)
{
    __shared__ char smem[LDSTOT];
    const int tid  = threadIdx.x;
    const int wv   = tid >> 6, lane = tid & 63;
    const int quad = lane >> 4, l15 = lane & 15;
    const int grp  = wv & 1, half = wv >> 1;
    const int b    = blockIdx.x >> 7, it = blockIdx.x & 127;
    const long rowbase = (long)b * NPIX + it * 32 + grp * 16;
    const float sgamma = gamma_p[0];

    // G fragment (bf16, pre-scaled by log2e): real k<8 in quad-0 lanes
    bf16x8 gfrag = zero8();
    if (lane < 16) gfrag = *(const bf16x8*)(gq + (rowbase + lane) * 8);

    // staging plan: 1280 x 16B chunks/round (2 halves x (F 2KB + Ht 8KB)), 5/thr
    const char* gPtr[5]; int ldsOff[5], ldsDlt[5], gStep[5];
    #pragma unroll
    for (int k = 0; k < 5; ++k) {
        int ch = k * 256 + tid;                 // 0..1279
        if (ch < 256) {                         // F: [128 j][16 B] contiguous
            int h = ch >> 7, c4 = ch & 127;
            ldsOff[k] = FBASE + h * 2 * 2048 + c4 * 16;
            ldsDlt[k] = 2048;
            gPtr[k]   = (const char*)fq + (long)(b * NPIX + h * 2048) * 16 + c4 * 16;
            gStep[k]  = 128 * 16;
        } else {                                // Ht: 64 rows x 128 B, stride 144
            int q = ch - 256;                   // 0..1023
            int h = q >> 9, r = q & 511, c = r >> 3, j16 = r & 7;
            ldsOff[k] = HBASE + h * 2 * 9216 + c * 144 + j16 * 16;
            ldsDlt[k] = 9216;
            gPtr[k]   = (const char*)hT + ((long)b * 64 + c) * NPIX
                        + h * 2048 + j16 * 16;
            gStep[k]  = 128;
        }
    }

    floatx4 acc[5];                             // [0..3]=O channels, [4]=den
    #pragma unroll
    for (int nt = 0; nt < 5; ++nt) acc[nt] = (floatx4){0.f, 0.f, 0.f, 0.f};
    const along ones = 0x3838383838383838L;     // fp8 e4m3 1.0 x8
    char* Pw = smem + PBASE + wv * 2176;        // wave-private P: 16 x 136 B

    // stage tile 0
    #pragma unroll
    for (int k = 0; k < 5; ++k) {
        *(afloat4*)(smem + ldsOff[k]) = *(const float4*)gPtr[k];
        gPtr[k] += gStep[k];
    }
    __syncthreads();

    for (int t = 0; t < 16; ++t) {
        const int buf = t & 1;
        float4 pre[5];
        if (t < 15) {
            #pragma unroll
            for (int k = 0; k < 5; ++k) {
                pre[k] = *(const float4*)gPtr[k];
                gPtr[k] += gStep[k];
            }
        }
        const char* Fb = smem + FBASE + (half * 2 + buf) * 2048;
        const char* Hb = smem + HBASE + (half * 2 + buf) * 9216;

        // --- S^T = F·G^T (bf16), exp2, pack fp8 -> P ---
        #pragma unroll
        for (int js = 0; js < 8; ++js) {
            bf16x8 afrag = zero8();
            if (lane < 16) afrag = *(const bf16x8*)(Fb + (js * 16 + l15) * 16);
            floatx4 s = __builtin_amdgcn_mfma_f32_16x16x32_bf16(
                afrag, gfrag, (floatx4){0.f, 0.f, 0.f, 0.f}, 0, 0, 0);
            float e0 = exp2f(s[0]), e1 = exp2f(s[1]);
            float e2 = exp2f(s[2]), e3 = exp2f(s[3]);
            int pk = __builtin_amdgcn_cvt_pk_fp8_f32(e0, e1, 0, false);
            pk     = __builtin_amdgcn_cvt_pk_fp8_f32(e2, e3, pk, true);
            *(aint*)(Pw + l15 * 136 + js * 16 + quad * 4) = pk;
        }
        asm volatile("" ::: "memory");          // P writes before P reads
        // --- O += P·Ht, den += P·1 (fp8 MFMA, b64 fragments) ---
        #pragma unroll
        for (int ks = 0; ks < 4; ++ks) {
            along pfrag = *(const along*)(Pw + l15 * 136 + ks * 32 + quad * 8);
            #pragma unroll
            for (int nt = 0; nt < 4; ++nt) {
                along bfrag = *(const along*)(Hb + (nt * 16 + l15) * 144 + ks * 32 + quad * 8);
                acc[nt] = __builtin_amdgcn_mfma_f32_16x16x32_fp8_fp8(pfrag, bfrag, acc[nt], 0, 0, 0);
            }
            acc[4] = __builtin_amdgcn_mfma_f32_16x16x32_fp8_fp8(pfrag, ones, acc[4], 0, 0, 0);
        }
        __syncthreads();                        // all reads of this buf done
        if (t < 15) {
            #pragma unroll
            for (int k = 0; k < 5; ++k)
                *(afloat4*)(smem + ldsOff[k] + (buf ^ 1) * ldsDlt[k]) = pre[k];
        }
        __syncthreads();                        // buf^1 filled
    }

    // cross-half combine (plain sums — no softmax rescale). red aliases the
    // stage region: safe, all waves passed the final barrier above.
    float* red = (float*)smem;                  // [grp][16 i][68]: 64 ch + den
    if (half == 0) {
        #pragma unroll
        for (int nt = 0; nt < 4; ++nt)
            #pragma unroll
            for (int r = 0; r < 4; ++r)
                red[grp * 1088 + (quad * 4 + r) * 68 + nt * 16 + l15] = acc[nt][r];
        if (l15 == 0) {
            #pragma unroll
            for (int r = 0; r < 4; ++r)
                red[grp * 1088 + (quad * 4 + r) * 68 + 64] = acc[4][r];
        }
    }
    __syncthreads();
    if (half == 1) {
        float rden[4];
        #pragma unroll
        for (int r = 0; r < 4; ++r)
            rden[r] = 1.0f / (acc[4][r] + red[grp * 1088 + (quad * 4 + r) * 68 + 64]);
        #pragma unroll
        for (int nt = 0; nt < 4; ++nt) {
            #pragma unroll
            for (int r = 0; r < 4; ++r) {
                float num = acc[nt][r] + red[grp * 1088 + (quad * 4 + r) * 68 + nt * 16 + l15];
                long off = (rowbase + quad * 4 + r) * 64 + nt * 16 + l15;
                out[off] = sgamma * (num * rden[r]) + x[off];
            }
        }
    }
}

extern "C" void kernel_launch(void* const* d_in, const int* in_sizes, int n_in,
                              void* d_out, int out_size, void* d_ws, size_t ws_size,
                              hipStream_t stream) {
    const float* x     = (const float*)d_in[0];
    const float* w_f   = (const float*)d_in[1];
    const float* b_f   = (const float*)d_in[2];
    const float* w_g   = (const float*)d_in[3];
    const float* b_g   = (const float*)d_in[4];
    const float* w_h   = (const float*)d_in[5];
    const float* b_h   = (const float*)d_in[6];
    const float* gamma = (const float*)d_in[7];
    float* out = (float*)d_out;

    bf16* fq = (bf16*)d_ws;                           // 16384*8 bf16
    bf16* gq = fq + 16384 * 8;                        // 16384*8 bf16 (x log2e)
    unsigned char* hT = (unsigned char*)(gq + 16384 * 8);  // 4*64*4096 fp8

    proj_kernel<<<256, 256, 0, stream>>>(x, w_f, b_f, w_g, b_g, w_h, b_h, fq, gq, hT);
    attn_kernel<<<512, 256, 0, stream>>>(fq, gq, hT, x, gamma, out);
}

// Round 6
// 113.914 us; speedup vs baseline: 1.1420x; 1.1420x over previous
//
#include <hip/hip_runtime.h>
#include <hip/hip_bf16.h>

typedef __bf16 bf16;
typedef __bf16 bf16x8 __attribute__((ext_vector_type(8)));
typedef __bf16 bf16x4 __attribute__((ext_vector_type(4)));
typedef float floatx4 __attribute__((ext_vector_type(4)));

// may_alias: LDS P-buffer is written as int (fp8 pack) and read as long
// (MFMA fragment) with NO barrier between (wave-private). Without may_alias,
// TBAA lets the compiler reorder the ds_read above the ds_write (round-3 NaN).
typedef int    aint    __attribute__((may_alias));
typedef long   along   __attribute__((may_alias));
typedef float4 afloat4 __attribute__((may_alias));

#define NPIX 4096
#define BATCH 4
#define LOG2E 1.4426950408889634f

__device__ inline bf16x8 zero8() {
    bf16x8 v;
    #pragma unroll
    for (int i = 0; i < 8; ++i) v[i] = (bf16)0.0f;
    return v;
}

// ---------------------------------------------------------------------------
// Kernel 1: projections via MFMA.  X[16384x64] @ W[64x80] ->
//   fq [16384][8] bf16, gq [16384][8] bf16 (PRE-SCALED by log2e),
//   hT [4][64][4096] fp8 e4m3.
// ---------------------------------------------------------------------------
__global__ __launch_bounds__(256) void proj_kernel(
    const float* __restrict__ x,
    const float* __restrict__ w_f, const float* __restrict__ b_f,
    const float* __restrict__ w_g, const float* __restrict__ b_g,
    const float* __restrict__ w_h, const float* __restrict__ b_h,
    bf16* __restrict__ fq, bf16* __restrict__ gq, unsigned char* __restrict__ hT)
{
    __shared__ bf16 xs[64 * 72];
    __shared__ bf16 wt[80 * 72];
    __shared__ float bs[80];
    const int tid = threadIdx.x;
    const int p0 = blockIdx.x * 64;

    {   // stage x tile 64x64 f32 -> bf16
        const float4* xg = (const float4*)(x + (long)p0 * 64);
        #pragma unroll
        for (int it = 0; it < 4; ++it) {
            int i4 = tid + it * 256;
            float4 v = xg[i4];
            int row = i4 >> 4, c4 = (i4 & 15) * 4;
            bf16x4 pk;
            pk[0] = (bf16)v.x; pk[1] = (bf16)v.y; pk[2] = (bf16)v.z; pk[3] = (bf16)v.w;
            *(bf16x4*)(&xs[row * 72 + c4]) = pk;
        }
    }
    for (int idx = tid; idx < 80 * 64; idx += 256) {
        int n = idx >> 6, c = idx & 63;
        float v = (n < 8) ? w_f[c * 8 + n]
                : (n < 16) ? w_g[c * 8 + (n - 8)]
                : w_h[c * 64 + (n - 16)];
        wt[n * 72 + c] = (bf16)v;
    }
    if (tid < 80)
        bs[tid] = (tid < 8) ? b_f[tid] : (tid < 16) ? b_g[tid - 8] : b_h[tid - 16];
    __syncthreads();

    const int wv = tid >> 6, lane = tid & 63;
    const int quad = lane >> 4, l15 = lane & 15;
    const int b = blockIdx.x >> 6;
    const int n0pix = (p0 & (NPIX - 1)) + wv * 16 + quad * 4;

    bf16x8 a0 = *(const bf16x8*)(&xs[(wv * 16 + l15) * 72 + quad * 8]);
    bf16x8 a1 = *(const bf16x8*)(&xs[(wv * 16 + l15) * 72 + 32 + quad * 8]);

    #pragma unroll
    for (int nt = 0; nt < 5; ++nt) {
        float bias = bs[nt * 16 + l15];
        floatx4 acc = {bias, bias, bias, bias};
        bf16x8 b0 = *(const bf16x8*)(&wt[(nt * 16 + l15) * 72 + quad * 8]);
        bf16x8 b1 = *(const bf16x8*)(&wt[(nt * 16 + l15) * 72 + 32 + quad * 8]);
        acc = __builtin_amdgcn_mfma_f32_16x16x32_bf16(a0, b0, acc, 0, 0, 0);
        acc = __builtin_amdgcn_mfma_f32_16x16x32_bf16(a1, b1, acc, 0, 0, 0);
        if (nt == 0) {
            #pragma unroll
            for (int r = 0; r < 4; ++r) {
                long P = (long)p0 + wv * 16 + quad * 4 + r;
                if (l15 < 8) fq[P * 8 + l15] = (bf16)acc[r];
                else         gq[P * 8 + (l15 - 8)] = (bf16)(acc[r] * LOG2E);
            }
        } else {
            int c = nt * 16 + l15 - 16;
            int pk = __builtin_amdgcn_cvt_pk_fp8_f32(acc[0], acc[1], 0, false);
            pk     = __builtin_amdgcn_cvt_pk_fp8_f32(acc[2], acc[3], pk, true);
            *(aint*)(hT + ((long)b * 64 + c) * NPIX + n0pix) = pk;
        }
    }
}

// ---------------------------------------------------------------------------
// Kernel 2: fp8 MFMA flash attention PARTIALS (no-rescale softmax => num/den
// partial sums over j are associative => j split across blocks).
// Grid 1024 = jsplit(4) x [B(4) x i-tiles(64 of 64 rows)]. Block 256 = 4
// waves; waves split the 64 i-rows (16 each) and SHARE the staged j-tile
// (F 2KB + Ht 8KB per buffer -> LDS 29.2KB -> 4 blocks/CU at grid 1024).
// Ht LDS: 64 rows x 128B, 16B units XOR-swizzled by (row&7): b128 staging
// writes conflict-free, PV b64 reads 2-way (free).
// Per block: 8 j-tiles of 128. Partials (num[64],den) -> ws, fp32.
// ---------------------------------------------------------------------------
#define FBASE 0                 // 2 x 2048 = 4096
#define HBASE 4096              // 2 x 8192 = 16384
#define PBASE 20480             // 4 x 2176 = 8704
#define LDSTOT 29184

__global__ __launch_bounds__(256) void attn_kernel(
    const bf16* __restrict__ fq, const bf16* __restrict__ gq,
    const unsigned char* __restrict__ hT, float* __restrict__ partial)
{
    __shared__ char smem[LDSTOT];
    const int tid  = threadIdx.x;
    const int wv   = tid >> 6, lane = tid & 63;
    const int quad = lane >> 4, l15 = lane & 15;
    const int js   = blockIdx.x >> 8;           // j-slice 0..3
    const int ib   = blockIdx.x & 255;          // b*64 + it
    const int b    = ib >> 6, it = ib & 63;
    const long rowbase = (long)b * NPIX + it * 64 + wv * 16;   // wave's 16 i rows
    const int jbase = js * 1024;                // slice j range: [jbase, +1024)

    // G fragment (bf16, pre-scaled by log2e): real k<8 in quad-0 lanes
    bf16x8 gfrag = zero8();
    if (lane < 16) gfrag = *(const bf16x8*)(gq + (rowbase + lane) * 8);

    // staging: 640 x 16B chunks per tile (F 128 + Ht 512); <=3 per thread
    const char* gp[3]; int lo[3], dlt[3], gstep[3]; bool act[3];
    #pragma unroll
    for (int k = 0; k < 3; ++k) {
        int ch = k * 256 + tid;
        act[k] = (ch < 640);
        if (ch < 128) {                         // F: [128 j][16B] contiguous
            lo[k]   = FBASE + ch * 16;
            dlt[k]  = 2048;
            gp[k]   = (const char*)fq + ((long)b * NPIX + jbase) * 16 + ch * 16;
            gstep[k] = 128 * 16;
        } else {                                // Ht: row c, unit u (swizzled)
            int q = (ch - 128) & 511;           // harmless for inactive
            int c = q >> 3, u = q & 7;
            lo[k]   = HBASE + c * 128 + ((u ^ (c & 7)) << 4);
            dlt[k]  = 8192;
            gp[k]   = (const char*)hT + ((long)b * 64 + c) * NPIX + jbase + u * 16;
            gstep[k] = 128;
        }
    }

    floatx4 acc[5];                             // [0..3]=O channels, [4]=den
    #pragma unroll
    for (int nt = 0; nt < 5; ++nt) acc[nt] = (floatx4){0.f, 0.f, 0.f, 0.f};
    const along ones = 0x3838383838383838L;     // fp8 e4m3 1.0 x8
    char* Pw = smem + PBASE + wv * 2176;        // wave-private P: 16 x 136 B

    // stage tile 0
    #pragma unroll
    for (int k = 0; k < 3; ++k)
        if (act[k]) {
            *(afloat4*)(smem + lo[k]) = *(const float4*)gp[k];
            gp[k] += gstep[k];
        }
    __syncthreads();

    for (int t = 0; t < 8; ++t) {
        const int buf = t & 1;
        float4 pre[3];
        if (t < 7) {
            #pragma unroll
            for (int k = 0; k < 3; ++k)
                if (act[k]) { pre[k] = *(const float4*)gp[k]; gp[k] += gstep[k]; }
        }
        const char* Fb = smem + FBASE + buf * 2048;
        const char* Hb = smem + HBASE + buf * 8192;

        // --- S^T = F·G^T (bf16), exp2, pack fp8 -> P (waves share F) ---
        #pragma unroll
        for (int j8 = 0; j8 < 8; ++j8) {
            bf16x8 afrag = zero8();
            if (lane < 16) afrag = *(const bf16x8*)(Fb + (j8 * 16 + l15) * 16);
            floatx4 s = __builtin_amdgcn_mfma_f32_16x16x32_bf16(
                afrag, gfrag, (floatx4){0.f, 0.f, 0.f, 0.f}, 0, 0, 0);
            float e0 = __builtin_amdgcn_exp2f(s[0]);
            float e1 = __builtin_amdgcn_exp2f(s[1]);
            float e2 = __builtin_amdgcn_exp2f(s[2]);
            float e3 = __builtin_amdgcn_exp2f(s[3]);
            int pk = __builtin_amdgcn_cvt_pk_fp8_f32(e0, e1, 0, false);
            pk     = __builtin_amdgcn_cvt_pk_fp8_f32(e2, e3, pk, true);
            *(aint*)(Pw + l15 * 136 + j8 * 16 + quad * 4) = pk;
        }
        asm volatile("" ::: "memory");          // P writes before P reads
        // --- O += P·Ht, den += P·1 (fp8 MFMA) ---
        #pragma unroll
        for (int ks = 0; ks < 4; ++ks) {
            along pfrag = *(const along*)(Pw + l15 * 136 + ks * 32 + quad * 8);
            #pragma unroll
            for (int nt = 0; nt < 4; ++nt) {
                int row = nt * 16 + l15;
                int unit = 2 * ks + (quad >> 1);
                along bfrag = *(const along*)(Hb + row * 128
                              + ((unit ^ (row & 7)) << 4) + (quad & 1) * 8);
                acc[nt] = __builtin_amdgcn_mfma_f32_16x16x32_fp8_fp8(pfrag, bfrag, acc[nt], 0, 0, 0);
            }
            acc[4] = __builtin_amdgcn_mfma_f32_16x16x32_fp8_fp8(pfrag, ones, acc[4], 0, 0, 0);
        }
        __syncthreads();                        // all reads of this buf done
        if (t < 7) {
            #pragma unroll
            for (int k = 0; k < 3; ++k)
                if (act[k])
                    *(afloat4*)(smem + lo[k] + (buf ^ 1) * dlt[k]) = pre[k];
        }
        __syncthreads();                        // buf^1 filled
    }

    // write partials straight from regs: partial[js][i][68] (64 num + den)
    float* pb = partial + ((long)js * (BATCH * NPIX) + rowbase) * 68;
    #pragma unroll
    for (int nt = 0; nt < 4; ++nt)
        #pragma unroll
        for (int r = 0; r < 4; ++r)
            pb[(quad * 4 + r) * 68 + nt * 16 + l15] = acc[nt][r];
    if (l15 == 0) {
        #pragma unroll
        for (int r = 0; r < 4; ++r)
            pb[(quad * 4 + r) * 68 + 64] = acc[4][r];
    }
}

// ---------------------------------------------------------------------------
// Kernel 3: reduce 4 j-slice partials -> out = (gamma/den)*num + x
// 512 blocks x 256 thr; 8 threads per pixel row (8 channels each).
// ---------------------------------------------------------------------------
__global__ __launch_bounds__(256) void reduce_kernel(
    const float* __restrict__ partial, const float* __restrict__ x,
    const float* __restrict__ gamma_p, float* __restrict__ out)
{
    const int tid = threadIdx.x;
    const long i  = (long)blockIdx.x * 32 + (tid >> 3);
    const int c0  = (tid & 7) * 8;
    const float* p = partial + i * 68;
    float4 n0 = {0.f, 0.f, 0.f, 0.f}, n1 = {0.f, 0.f, 0.f, 0.f};
    float den = 0.f;
    #pragma unroll
    for (int js = 0; js < 4; ++js) {
        const float* pj = p + (long)js * (BATCH * NPIX) * 68;
        float4 a = *(const float4*)(pj + c0);
        float4 c = *(const float4*)(pj + c0 + 4);
        n0.x += a.x; n0.y += a.y; n0.z += a.z; n0.w += a.w;
        n1.x += c.x; n1.y += c.y; n1.z += c.z; n1.w += c.w;
        den += pj[64];
    }
    const float rd = gamma_p[0] / den;
    const float* xr = x + i * 64 + c0;
    float* orow = out + i * 64 + c0;
    float4 xa = *(const float4*)xr, xb = *(const float4*)(xr + 4);
    float4 oa, ob;
    oa.x = n0.x * rd + xa.x; oa.y = n0.y * rd + xa.y;
    oa.z = n0.z * rd + xa.z; oa.w = n0.w * rd + xa.w;
    ob.x = n1.x * rd + xb.x; ob.y = n1.y * rd + xb.y;
    ob.z = n1.z * rd + xb.z; ob.w = n1.w * rd + xb.w;
    *(float4*)orow = oa; *(float4*)(orow + 4) = ob;
}

extern "C" void kernel_launch(void* const* d_in, const int* in_sizes, int n_in,
                              void* d_out, int out_size, void* d_ws, size_t ws_size,
                              hipStream_t stream) {
    const float* x     = (const float*)d_in[0];
    const float* w_f   = (const float*)d_in[1];
    const float* b_f   = (const float*)d_in[2];
    const float* w_g   = (const float*)d_in[3];
    const float* b_g   = (const float*)d_in[4];
    const float* w_h   = (const float*)d_in[5];
    const float* b_h   = (const float*)d_in[6];
    const float* gamma = (const float*)d_in[7];
    float* out = (float*)d_out;

    bf16* fq = (bf16*)d_ws;                                // 16384*8 bf16
    bf16* gq = fq + 16384 * 8;                             // 16384*8 bf16 (x log2e)
    unsigned char* hT = (unsigned char*)(gq + 16384 * 8);  // 4*64*4096 fp8
    float* partial = (float*)(hT + (long)BATCH * 64 * NPIX); // 4*16384*68 f32

    proj_kernel<<<256, 256, 0, stream>>>(x, w_f, b_f, w_g, b_g, w_h, b_h, fq, gq, hT);
    attn_kernel<<<1024, 256, 0, stream>>>(fq, gq, hT, partial);
    reduce_kernel<<<512, 256, 0, stream>>>(partial, x, gamma, out);
}